// Round 1
// baseline (534.237 us; speedup 1.0000x reference)
//
#include <hip/hip_runtime.h>
#include <math.h>

// Problem constants (fixed by setup_inputs): B=8, N=65536, D=64, iterations=10
#define B_    8
#define N_    65536
#define D_    64
#define ITERS 10

#define NBLK  128                 // chunks per batch -> grid = 128*8 = 1024 blocks
#define CHUNK (N_ / NBLK)         // 512 rows per block
#define GROUPS 16                 // 256 threads / 16 lanes-per-row
#define ROWS_PER_GROUP (CHUNK / GROUPS)  // 32

// ---------------------------------------------------------------------------
// Phase 1: each block does an online-softmax partial over its 512 rows.
// 16 lanes per row: lane holds float4 slice of D=64. A wave covers 4
// consecutive rows => 1 KiB contiguous coalesced loads.
// Base-2 softmax: t_n = c2 * ||z - m_n||^2 with c2 = inv_temp*log2(e);
// exactly equivalent to softmax(inv_temp*d2) after normalization.
// ---------------------------------------------------------------------------
__global__ __launch_bounds__(256) void gmm_phase1(
    const float* __restrict__ z,       // [B,D]
    const float* __restrict__ means,   // [B,N,D]
    const float* __restrict__ sigma_p, // [1]
    float* __restrict__ pm,            // [B,NBLK]
    float* __restrict__ pl,            // [B,NBLK]
    float* __restrict__ pacc)          // [B,NBLK,D]
{
    const int blk  = blockIdx.x;
    const int b    = blockIdx.y;
    const int tid  = threadIdx.x;
    const int grp  = tid >> 4;   // 0..15
    const int lane = tid & 15;   // 0..15

    const float sigma = sigma_p[0];
    const float c2 = (-0.5f / (sigma * sigma)) * 1.44269504088896340736f;

    // z slice for this lane (same for every row this group processes)
    const float4 zv = *(const float4*)(z + b * D_ + lane * 4);

    float m = -INFINITY;
    float l = 0.0f;
    float ax = 0.0f, ay = 0.0f, az = 0.0f, aw = 0.0f;

    const float* base = means + (size_t)b * N_ * D_;
    const int row0 = blk * CHUNK + grp;

#pragma unroll 4
    for (int i = 0; i < ROWS_PER_GROUP; ++i) {
        const int n = row0 + i * GROUPS;
        const float4 mv = *(const float4*)(base + (size_t)n * D_ + lane * 4);

        const float dx = zv.x - mv.x;
        const float dy = zv.y - mv.y;
        const float dz = zv.z - mv.z;
        const float dw = zv.w - mv.w;
        float s = dx * dx + dy * dy + dz * dz + dw * dw;
        // reduce across the 16 lanes of this row-group (subgroup-aligned xor)
        s += __shfl_xor(s, 1);
        s += __shfl_xor(s, 2);
        s += __shfl_xor(s, 4);
        s += __shfl_xor(s, 8);

        const float t  = c2 * s;
        const float mn = fmaxf(m, t);
        const float sc = exp2f(m - mn);   // == 0 when m == -inf
        const float w  = exp2f(t - mn);
        l  = l * sc + w;
        ax = ax * sc + w * mv.x;
        ay = ay * sc + w * mv.y;
        az = az * sc + w * mv.z;
        aw = aw * sc + w * mv.w;
        m  = mn;
    }

    // ---- block-level merge of the 16 group states via LDS ----
    __shared__ float s_m[GROUPS];
    __shared__ float s_l[GROUPS];
    __shared__ float s_acc[GROUPS][D_];

    if (lane == 0) { s_m[grp] = m; s_l[grp] = l; }
    s_acc[grp][lane * 4 + 0] = ax;
    s_acc[grp][lane * 4 + 1] = ay;
    s_acc[grp][lane * 4 + 2] = az;
    s_acc[grp][lane * 4 + 3] = aw;
    __syncthreads();

    if (tid < D_) {
        float M = -INFINITY;
#pragma unroll
        for (int g = 0; g < GROUPS; ++g) M = fmaxf(M, s_m[g]);
        float L = 0.0f;
        float a = 0.0f;
#pragma unroll
        for (int g = 0; g < GROUPS; ++g) {
            const float wg = exp2f(s_m[g] - M);
            L += wg * s_l[g];
            a += wg * s_acc[g][tid];
        }
        const int pidx = b * NBLK + blk;
        pacc[(size_t)pidx * D_ + tid] = a;
        if (tid == 0) { pm[pidx] = M; pl[pidx] = L; }
    }
}

// ---------------------------------------------------------------------------
// Phase 2: merge the NBLK partials per batch, emit z_new. Tiny kernel.
// ---------------------------------------------------------------------------
__global__ __launch_bounds__(64) void gmm_phase2(
    const float* __restrict__ pm,
    const float* __restrict__ pl,
    const float* __restrict__ pacc,
    float* __restrict__ z_out,       // ws z buffer [B,D]
    float* __restrict__ final_out)   // d_out on last iteration, else nullptr
{
    const int b = blockIdx.x;
    const int d = threadIdx.x;

    float M = -INFINITY;
    for (int k = 0; k < NBLK; ++k) M = fmaxf(M, pm[b * NBLK + k]);

    float L = 0.0f, a = 0.0f;
    for (int k = 0; k < NBLK; ++k) {
        const float wg = exp2f(pm[b * NBLK + k] - M);
        L += wg * pl[b * NBLK + k];
        a += wg * pacc[(size_t)(b * NBLK + k) * D_ + d];
    }
    const float zv = a / L;
    z_out[b * D_ + d] = zv;
    if (final_out) final_out[b * D_ + d] = zv;
}

// ---------------------------------------------------------------------------
extern "C" void kernel_launch(void* const* d_in, const int* in_sizes, int n_in,
                              void* d_out, int out_size, void* d_ws, size_t ws_size,
                              hipStream_t stream)
{
    // inputs: 0:x [B,D] (unused), 1:z [B,D], 2:means [B,N,D], 3:sigma [1], 4:iterations [1]
    const float* z0    = (const float*)d_in[1];
    const float* means = (const float*)d_in[2];
    const float* sigma = (const float*)d_in[3];
    float* out = (float*)d_out;

    float* ws   = (float*)d_ws;
    float* pm   = ws;                        // B*NBLK
    float* pl   = pm + B_ * NBLK;            // B*NBLK
    float* pacc = pl + B_ * NBLK;            // B*NBLK*D
    float* zbuf = pacc + (size_t)B_ * NBLK * D_;  // B*D

    for (int it = 0; it < ITERS; ++it) {
        const float* zin = (it == 0) ? z0 : zbuf;
        gmm_phase1<<<dim3(NBLK, B_), 256, 0, stream>>>(zin, means, sigma, pm, pl, pacc);
        gmm_phase2<<<B_, 64, 0, stream>>>(pm, pl, pacc, zbuf,
                                          (it == ITERS - 1) ? out : nullptr);
    }
}

// Round 2
// 454.224 us; speedup vs baseline: 1.1762x; 1.1762x over previous
//
#include <hip/hip_runtime.h>
#include <math.h>

// Problem constants (fixed by setup_inputs): B=8, N=65536, D=64, iterations=10
#define B_    8
#define N_    65536
#define D_    64
#define ITERS 10

#define NBLK  256                 // chunks per batch -> grid = 256*8 = 2048 blocks
#define CHUNK (N_ / NBLK)         // 256 rows per block
#define GROUPS 16                 // 256 threads / 16 lanes-per-row
#define KSTATES 4                 // independent online-softmax states per group
#define JITER (CHUNK / (GROUPS * KSTATES))  // 4 outer steps, 64 rows each

// ---------------------------------------------------------------------------
// Phase 1: per-block online-softmax partial over its 256 rows.
// 16 lanes per row (lane = float4 slice of D=64). 4 INDEPENDENT states per
// group break the serial softmax chain -> >=4 coalesced 1KB wave-loads in
// flight (Little's law at HBM latency). Explicit cur/nxt double buffer.
// Base-2 domain: t = c2 * d2, c2 = -0.5/sigma^2 * log2(e).
// ---------------------------------------------------------------------------
__global__ __launch_bounds__(256) void gmm_phase1(
    const float* __restrict__ z,       // [B,D]
    const float* __restrict__ means,   // [B,N,D]
    const float* __restrict__ sigma_p, // [1]
    float* __restrict__ pm,            // [B,NBLK]
    float* __restrict__ pl,            // [B,NBLK]
    float* __restrict__ pacc)          // [B,NBLK,D]
{
    const int blk  = blockIdx.x;
    const int b    = blockIdx.y;
    const int tid  = threadIdx.x;
    const int grp  = tid >> 4;   // 0..15
    const int lane = tid & 15;   // 0..15

    const float sigma = sigma_p[0];
    const float c2 = (-0.5f / (sigma * sigma)) * 1.44269504088896340736f;

    const float4 zv = *(const float4*)(z + b * D_ + lane * 4);

    // row(j,k) = blk*CHUNK + j*64 + k*16 + grp   (load k covers 4 consecutive
    // rows across a wave's 4 groups -> 1KB contiguous per load instruction)
    const float* rowbase = means + ((size_t)b * N_ + (size_t)blk * CHUNK + grp) * D_;
    const float4* p = (const float4*)rowbase + lane;
    // float4 strides: row = 16, k-step (16 rows) = 256, j-step (64 rows) = 1024

    float  m[KSTATES], l[KSTATES];
    float4 acc[KSTATES];
#pragma unroll
    for (int k = 0; k < KSTATES; ++k) {
        m[k] = -INFINITY; l[k] = 0.0f;
        acc[k] = make_float4(0.f, 0.f, 0.f, 0.f);
    }

    float4 cur[KSTATES];
#pragma unroll
    for (int k = 0; k < KSTATES; ++k) cur[k] = p[k * 256];

#pragma unroll
    for (int j = 0; j < JITER; ++j) {
        float4 nxt[KSTATES];
        if (j + 1 < JITER) {
#pragma unroll
            for (int k = 0; k < KSTATES; ++k) nxt[k] = p[(j + 1) * 1024 + k * 256];
        }
#pragma unroll
        for (int k = 0; k < KSTATES; ++k) {
            const float4 mv = cur[k];
            const float dx = zv.x - mv.x;
            const float dy = zv.y - mv.y;
            const float dz = zv.z - mv.z;
            const float dw = zv.w - mv.w;
            float s = dx * dx + dy * dy + dz * dz + dw * dw;
            s += __shfl_xor(s, 1);
            s += __shfl_xor(s, 2);
            s += __shfl_xor(s, 4);
            s += __shfl_xor(s, 8);

            const float t  = c2 * s;
            const float mn = fmaxf(m[k], t);
            const float sc = exp2f(m[k] - mn);
            const float w  = exp2f(t - mn);
            l[k]  = l[k] * sc + w;
            acc[k].x = acc[k].x * sc + w * mv.x;
            acc[k].y = acc[k].y * sc + w * mv.y;
            acc[k].z = acc[k].z * sc + w * mv.z;
            acc[k].w = acc[k].w * sc + w * mv.w;
            m[k] = mn;
        }
#pragma unroll
        for (int k = 0; k < KSTATES; ++k) cur[k] = nxt[k];
    }

    // merge the 4 per-lane states (m,l group-uniform; acc lane-specific)
    float M = fmaxf(fmaxf(m[0], m[1]), fmaxf(m[2], m[3]));
    float L = 0.0f;
    float ax = 0.f, ay = 0.f, az = 0.f, aw = 0.f;
#pragma unroll
    for (int k = 0; k < KSTATES; ++k) {
        const float wk = exp2f(m[k] - M);
        L  += wk * l[k];
        ax += wk * acc[k].x;
        ay += wk * acc[k].y;
        az += wk * acc[k].z;
        aw += wk * acc[k].w;
    }

    // ---- block-level merge of the 16 group states via LDS ----
    __shared__ float s_m[GROUPS];
    __shared__ float s_l[GROUPS];
    __shared__ float s_acc[GROUPS][D_];

    if (lane == 0) { s_m[grp] = M; s_l[grp] = L; }
    s_acc[grp][lane * 4 + 0] = ax;
    s_acc[grp][lane * 4 + 1] = ay;
    s_acc[grp][lane * 4 + 2] = az;
    s_acc[grp][lane * 4 + 3] = aw;
    __syncthreads();

    if (tid < D_) {
        float Mb = -INFINITY;
#pragma unroll
        for (int g = 0; g < GROUPS; ++g) Mb = fmaxf(Mb, s_m[g]);
        float Lb = 0.0f;
        float a  = 0.0f;
#pragma unroll
        for (int g = 0; g < GROUPS; ++g) {
            const float wg = exp2f(s_m[g] - Mb);
            Lb += wg * s_l[g];
            a  += wg * s_acc[g][tid];
        }
        const int pidx = b * NBLK + blk;
        pacc[(size_t)pidx * D_ + tid] = a;
        if (tid == 0) { pm[pidx] = Mb; pl[pidx] = Lb; }
    }
}

// ---------------------------------------------------------------------------
// Phase 2: merge NBLK=256 partials per batch. 8 blocks x 256 threads:
// thread t handles d = t&63, quarter q = t>>6 (64 partials each).
// ---------------------------------------------------------------------------
__global__ __launch_bounds__(256) void gmm_phase2(
    const float* __restrict__ pm,
    const float* __restrict__ pl,
    const float* __restrict__ pacc,
    float* __restrict__ z_out,       // ws z buffer [B,D]
    float* __restrict__ final_out)   // d_out on last iteration, else nullptr
{
    const int b = blockIdx.x;
    const int t = threadIdx.x;
    const int d = t & 63;
    const int q = t >> 6;

    __shared__ float s_red[256];
    __shared__ float s_L[4];

    s_red[t] = pm[b * NBLK + t];
    __syncthreads();
    for (int s = 128; s > 0; s >>= 1) {
        if (t < s) s_red[t] = fmaxf(s_red[t], s_red[t + s]);
        __syncthreads();
    }
    const float M = s_red[0];
    __syncthreads();

    float L = 0.0f, A = 0.0f;
    for (int k = 0; k < 64; ++k) {
        const int pi = b * NBLK + q * 64 + k;
        const float wg = exp2f(pm[pi] - M);
        L += wg * pl[pi];
        A += wg * pacc[(size_t)pi * D_ + d];
    }

    s_red[q * 64 + d] = A;
    if (d == 0) s_L[q] = L;
    __syncthreads();

    if (t < D_) {
        float As = s_red[t] + s_red[64 + t] + s_red[128 + t] + s_red[192 + t];
        float Ls = s_L[0] + s_L[1] + s_L[2] + s_L[3];
        const float zv = As / Ls;
        z_out[b * D_ + t] = zv;
        if (final_out) final_out[b * D_ + t] = zv;
    }
}

// ---------------------------------------------------------------------------
extern "C" void kernel_launch(void* const* d_in, const int* in_sizes, int n_in,
                              void* d_out, int out_size, void* d_ws, size_t ws_size,
                              hipStream_t stream)
{
    // inputs: 0:x (unused), 1:z [B,D], 2:means [B,N,D], 3:sigma [1], 4:iterations [1]
    const float* z0    = (const float*)d_in[1];
    const float* means = (const float*)d_in[2];
    const float* sigma = (const float*)d_in[3];
    float* out = (float*)d_out;

    float* ws   = (float*)d_ws;
    float* pm   = ws;                        // B*NBLK
    float* pl   = pm + B_ * NBLK;            // B*NBLK
    float* pacc = pl + B_ * NBLK;            // B*NBLK*D
    float* zbuf = pacc + (size_t)B_ * NBLK * D_;  // B*D

    for (int it = 0; it < ITERS; ++it) {
        const float* zin = (it == 0) ? z0 : zbuf;
        gmm_phase1<<<dim3(NBLK, B_), 256, 0, stream>>>(zin, means, sigma, pm, pl, pacc);
        gmm_phase2<<<B_, 256, 0, stream>>>(pm, pl, pacc, zbuf,
                                           (it == ITERS - 1) ? out : nullptr);
    }
}